// Round 18
// baseline (124.000 us; speedup 1.0000x reference)
//
#include <hip/hip_runtime.h>
#include <math.h>

#define N_NODES 50000
#define N_PAD   50048      // padded per-XCD slice stride
#define N_EDGES 600000
#define ALPHA 0.01f
#define KG_BLKS 782        // GEMM blocks (782*64 = 50048 >= 50000)
#define KEB_GRID 2048      // fused e+edge blocks
#define KP_GRID 64

typedef unsigned short u16;
typedef unsigned int u32;
using short8 = __attribute__((ext_vector_type(8))) short;
using f32x4  = __attribute__((ext_vector_type(4))) float;

__device__ __forceinline__ float leaky(float x) { return x > 0.f ? x : ALPHA * x; }

__device__ __forceinline__ u16 f2bf_rn(float x) {
    u32 u = __float_as_uint(x);
    u32 r = (u + 0x7FFFu + ((u >> 16) & 1u)) >> 16;
    return (u16)r;
}
__device__ __forceinline__ float bf2f(u16 b) { return __uint_as_float(((u32)b) << 16); }

// ====== KP: zero w8/hg8/counter + pack W_u into MFMA B-frag (bf16 hi/lo) + w_em ======
__global__ __launch_bounds__(256) void kp_prep(const float* __restrict__ Wu,
                                               const float* __restrict__ W_e,
                                               const float* __restrict__ W_m,
                                               u16* __restrict__ Bhi, u16* __restrict__ Blo,
                                               float* __restrict__ w8,
                                               float* __restrict__ hg8,
                                               float* __restrict__ w_em_g,
                                               int* __restrict__ counter) {
    int g = blockIdx.x * 256 + threadIdx.x;
    for (int i = g; i < 8 * N_PAD; i += KP_GRID * 256) w8[i] = 0.f;
    if (g < 1024) hg8[g] = 0.f;                  // 8 x 128 accumulator slices
    if (g == 0) *counter = 0;
    if (g < 2048) {
        int f = g >> 6;                          // nt*4+kt
        int L = g & 63;
        int nt = f >> 2, kt = f & 3;
        int kbase = kt * 32 + (L >> 4) * 8;
        int col = nt * 16 + (L & 15);
        #pragma unroll
        for (int j = 0; j < 8; ++j) {
            float x = Wu[(size_t)(kbase + j) * 128 + col];
            u16 hi = f2bf_rn(x);
            u16 lo = f2bf_rn(x - bf2f(hi));
            Bhi[(size_t)g * 8 + j] = hi;
            Blo[(size_t)g * 8 + j] = lo;
        }
    }
    if (g >= 2048 && g < 2112) {                 // 64 threads: w_em = W_e @ W_m
        int r = g - 2048;
        float acc = 0.f;
        const float* row = W_e + r * 128;
        #pragma unroll 8
        for (int k = 0; k < 128; ++k) acc += row[k] * W_m[k];
        w_em_g[r] = acc;
    }
}

// ================= KG: MFMA node GEMM -> ps, pd only (identical to R16) ==============
__global__ __launch_bounds__(256) void kg_gemm(
        const float* __restrict__ h, const float* __restrict__ a,
        const u16* __restrict__ Bhi, const u16* __restrict__ Blo,
        float* __restrict__ ps, float* __restrict__ pd) {
    __shared__ u16 sAhi[64 * 128];
    __shared__ u16 sAlo[64 * 128];
    __shared__ float sav[256];
    int t = threadIdx.x;
    int base = blockIdx.x * 64;
    if (t < 256) sav[t] = a[t];

    #pragma unroll
    for (int it = 0; it < 8; ++it) {
        int i = t + it * 256;
        int row = i >> 5, c4 = i & 31;
        float4 v = make_float4(0.f, 0.f, 0.f, 0.f);
        if (base + row < N_NODES)
            v = ((const float4*)h)[(size_t)(base + row) * 32 + c4];
        u16 h0 = f2bf_rn(v.x), h1 = f2bf_rn(v.y), h2 = f2bf_rn(v.z), h3 = f2bf_rn(v.w);
        u16 l0 = f2bf_rn(v.x - bf2f(h0)), l1 = f2bf_rn(v.y - bf2f(h1));
        u16 l2 = f2bf_rn(v.z - bf2f(h2)), l3 = f2bf_rn(v.w - bf2f(h3));
        uint2 whi = make_uint2((u32)h0 | ((u32)h1 << 16), (u32)h2 | ((u32)h3 << 16));
        uint2 wlo = make_uint2((u32)l0 | ((u32)l1 << 16), (u32)l2 | ((u32)l3 << 16));
        int idx = (row * 128 + c4 * 4) ^ ((row & 7) << 3);
        *(uint2*)(sAhi + idx) = whi;
        *(uint2*)(sAlo + idx) = wlo;
    }
    __syncthreads();

    int lane = t & 63;
    int wv = t >> 6;
    int khalf = lane >> 4;
    int l15 = lane & 15;

    short8 ahi[4], alo[4];
    {
        int rloc = wv * 16 + l15;
        #pragma unroll
        for (int kt = 0; kt < 4; ++kt) {
            int idx = (rloc * 128 + kt * 32 + khalf * 8) ^ ((rloc & 7) << 3);
            ahi[kt] = *(const short8*)(sAhi + idx);
            alo[kt] = *(const short8*)(sAlo + idx);
        }
    }

    float psum1[4] = {0.f, 0.f, 0.f, 0.f};
    float psum2[4] = {0.f, 0.f, 0.f, 0.f};

    #pragma unroll
    for (int nt = 0; nt < 8; ++nt) {
        f32x4 acc = {0.f, 0.f, 0.f, 0.f};
        #pragma unroll
        for (int kt = 0; kt < 4; ++kt) {
            size_t bi = ((size_t)(nt * 4 + kt) * 64 + lane) * 8;
            short8 bhi = *(const short8*)(Bhi + bi);
            short8 blo = *(const short8*)(Blo + bi);
            acc = __builtin_amdgcn_mfma_f32_16x16x32_bf16(ahi[kt], bhi, acc, 0, 0, 0);
            acc = __builtin_amdgcn_mfma_f32_16x16x32_bf16(alo[kt], bhi, acc, 0, 0, 0);
            acc = __builtin_amdgcn_mfma_f32_16x16x32_bf16(ahi[kt], blo, acc, 0, 0, 0);
        }
        int colg = nt * 16 + l15;
        float a1 = sav[colg], a2 = sav[128 + colg];
        #pragma unroll
        for (int r = 0; r < 4; ++r) {
            float o = leaky(acc[r]);
            psum1[r] += o * a1;
            psum2[r] += o * a2;
        }
    }

    #pragma unroll
    for (int r = 0; r < 4; ++r) {
        float p1 = psum1[r], p2 = psum2[r];
        #pragma unroll
        for (int m = 8; m >= 1; m >>= 1) {
            p1 += __shfl_xor(p1, m);
            p2 += __shfl_xor(p2, m);
        }
        if (l15 == 0) {
            int row = base + wv * 16 + khalf * 4 + r;
            if (row < N_NODES) { ps[row] = p1; pd[row] = p2; }
        }
    }
}

// ====== KEB: e-dot + sigmoid/exp + XCD-local w8 atomic + Spart (identical to R16) ====
__global__ __launch_bounds__(256) void keb_edge(
        const float* __restrict__ e, const float* __restrict__ w_em_g,
        const int* __restrict__ src, const int* __restrict__ dst,
        const float* __restrict__ ps, const float* __restrict__ pd,
        float* __restrict__ w8, double* __restrict__ Spart) {
    __shared__ float swem[64];
    int t = threadIdx.x;
    if (t < 64) swem[t] = w_em_g[t];
    __syncthreads();
    int lane = t & 63;
    int q = lane & 15;
    int g = lane >> 4;
    int gw = (blockIdx.x * 256 + t) >> 6;
    const int nw = KEB_GRID * 4;
    float4 wv = ((const float4*)swem)[q];
    float* wsl = w8 + (blockIdx.x & 7) * N_PAD;   // XCD-local slice

    double sacc = 0.0;
    for (int base = gw * 16; base < N_EDGES; base += nw * 16) {
        int o = base + g + 4 * (q & 3);           // finalize-edge for lanes with q<4
        int s  = src[o];
        int dd = dst[o];
        int e0 = base + g;                        // E%16==0 -> in range
        float4 v0 = ((const float4*)(e + (size_t)e0 * 64))[q];
        float4 v1 = ((const float4*)(e + (size_t)(e0 + 4) * 64))[q];
        float4 v2 = ((const float4*)(e + (size_t)(e0 + 8) * 64))[q];
        float4 v3 = ((const float4*)(e + (size_t)(e0 + 12) * 64))[q];
        float score = ps[s] + pd[dd];
        float sig = 1.f / (1.f + expf(-score));
        float d0 = v0.x * wv.x + v0.y * wv.y + v0.z * wv.z + v0.w * wv.w;
        float d1 = v1.x * wv.x + v1.y * wv.y + v1.z * wv.z + v1.w * wv.w;
        float d2 = v2.x * wv.x + v2.y * wv.y + v2.z * wv.z + v2.w * wv.w;
        float d3 = v3.x * wv.x + v3.y * wv.y + v3.z * wv.z + v3.w * wv.w;
        #pragma unroll
        for (int m = 1; m <= 8; m <<= 1) {
            d0 += __shfl_xor(d0, m);
            d1 += __shfl_xor(d1, m);
            d2 += __shfl_xor(d2, m);
            d3 += __shfl_xor(d3, m);
        }
        if (q < 4) {
            float dsel = (q == 0) ? d0 : (q == 1) ? d1 : (q == 2) ? d2 : d3;
            float p = expf(sig * dsel);
            atomicAdd(&wsl[s], p);
            sacc += (double)p;
        }
    }
    __shared__ double sred[256];
    sred[t] = sacc;
    __syncthreads();
    for (int s2_ = 128; s2_ > 0; s2_ >>= 1) {
        if (t < s2_) sred[t] += sred[t + s2_];
        __syncthreads();
    }
    if (t == 0) Spart[blockIdx.x] = sred[0];
}

// ====== KG2+KD: recompute GEMM -> hg8 atomics; LAST block (counter) runs the MLP =====
// Fence-free ordering: hg8 writes are device-scope atomics; __syncthreads drains
// vmcnt(0) (all atomics ack'd at coherence point) before the counter atomic; the
// last block reads hg8 via atomicAdd(p, 0.f) (coherence-point reads). NO threadfence.
struct G2S {
    u16 sAhi[64 * 128];
    u16 sAlo[64 * 128];
    float sw[64];
    float sredf[4][8][16];
};
struct TLS {
    double dred[256];
    float fpart[256];
    float hgs[128];
    float x1s[512];
    float x2s[128];
    float x3s[16];
};
union KG2U { G2S g; TLS tl; };

__global__ __launch_bounds__(256) void kg2_hg_tail(
        const float* __restrict__ h, const u16* __restrict__ Bhi,
        const u16* __restrict__ Blo, const float* __restrict__ w8,
        float* __restrict__ hg8, const double* __restrict__ Spart,
        int* __restrict__ counter,
        const float* __restrict__ W1, const float* __restrict__ b1,
        const float* __restrict__ W2, const float* __restrict__ b2,
        const float* __restrict__ W3, const float* __restrict__ b3,
        const float* __restrict__ W4, const float* __restrict__ b4,
        float* __restrict__ out) {
    __shared__ KG2U sm;
    __shared__ int islast;
    int t = threadIdx.x;
    int base = blockIdx.x * 64;
    if (t < 64) {
        float acc = 0.f;
        int r = base + t;
        if (r < N_NODES) {
            #pragma unroll
            for (int x = 0; x < 8; ++x) acc += w8[(size_t)x * N_PAD + r];
        }
        sm.g.sw[t] = acc;
    }

    #pragma unroll
    for (int it = 0; it < 8; ++it) {
        int i = t + it * 256;
        int row = i >> 5, c4 = i & 31;
        float4 v = make_float4(0.f, 0.f, 0.f, 0.f);
        if (base + row < N_NODES)
            v = ((const float4*)h)[(size_t)(base + row) * 32 + c4];
        u16 h0 = f2bf_rn(v.x), h1 = f2bf_rn(v.y), h2 = f2bf_rn(v.z), h3 = f2bf_rn(v.w);
        u16 l0 = f2bf_rn(v.x - bf2f(h0)), l1 = f2bf_rn(v.y - bf2f(h1));
        u16 l2 = f2bf_rn(v.z - bf2f(h2)), l3 = f2bf_rn(v.w - bf2f(h3));
        uint2 whi = make_uint2((u32)h0 | ((u32)h1 << 16), (u32)h2 | ((u32)h3 << 16));
        uint2 wlo = make_uint2((u32)l0 | ((u32)l1 << 16), (u32)l2 | ((u32)l3 << 16));
        int idx = (row * 128 + c4 * 4) ^ ((row & 7) << 3);
        *(uint2*)(sm.g.sAhi + idx) = whi;
        *(uint2*)(sm.g.sAlo + idx) = wlo;
    }
    __syncthreads();

    int lane = t & 63;
    int wv = t >> 6;
    int khalf = lane >> 4;
    int l15 = lane & 15;

    short8 ahi[4], alo[4];
    {
        int rloc = wv * 16 + l15;
        #pragma unroll
        for (int kt = 0; kt < 4; ++kt) {
            int idx = (rloc * 128 + kt * 32 + khalf * 8) ^ ((rloc & 7) << 3);
            ahi[kt] = *(const short8*)(sm.g.sAhi + idx);
            alo[kt] = *(const short8*)(sm.g.sAlo + idx);
        }
    }

    float wr[4];
    #pragma unroll
    for (int r = 0; r < 4; ++r) wr[r] = sm.g.sw[wv * 16 + khalf * 4 + r];

    #pragma unroll
    for (int nt = 0; nt < 8; ++nt) {
        f32x4 acc = {0.f, 0.f, 0.f, 0.f};
        #pragma unroll
        for (int kt = 0; kt < 4; ++kt) {
            size_t bi = ((size_t)(nt * 4 + kt) * 64 + lane) * 8;
            short8 bhi = *(const short8*)(Bhi + bi);
            short8 blo = *(const short8*)(Blo + bi);
            acc = __builtin_amdgcn_mfma_f32_16x16x32_bf16(ahi[kt], bhi, acc, 0, 0, 0);
            acc = __builtin_amdgcn_mfma_f32_16x16x32_bf16(alo[kt], bhi, acc, 0, 0, 0);
            acc = __builtin_amdgcn_mfma_f32_16x16x32_bf16(ahi[kt], blo, acc, 0, 0, 0);
        }
        float colsum = 0.f;
        #pragma unroll
        for (int r = 0; r < 4; ++r) colsum += leaky(acc[r]) * wr[r];
        colsum += __shfl_xor(colsum, 16);
        colsum += __shfl_xor(colsum, 32);
        if (khalf == 0) sm.g.sredf[wv][nt][l15] = colsum;
    }
    __syncthreads();
    if (t < 128) {
        int nt = t >> 4, l = t & 15;
        float s = sm.g.sredf[0][nt][l] + sm.g.sredf[1][nt][l] +
                  sm.g.sredf[2][nt][l] + sm.g.sredf[3][nt][l];
        atomicAdd(&hg8[(blockIdx.x & 7) * 128 + t], s);   // XCD-local slice
    }

    // ---- last-block detection (fence-free: barrier drains vmcnt -> atomics ack'd) ---
    __syncthreads();
    if (t == 0) {
        int prev = atomicAdd(counter, 1);
        islast = (prev == KG_BLKS - 1);
    }
    __syncthreads();
    if (!islast) return;

    // ================= tail: reduce S + hg8, then MLP (256 threads) ==================
    {
        double s = 0.0;
        for (int i = t; i < KEB_GRID; i += 256) s += Spart[i];
        sm.tl.dred[t] = s;
    }
    __syncthreads();
    for (int st = 128; st > 0; st >>= 1) {
        if (t < st) sm.tl.dred[t] += sm.tl.dred[t + st];
        __syncthreads();
    }
    double S = sm.tl.dred[0];
    __syncthreads();

    if (t < 128) {                                 // hg: coherence-point reads of hg8
        double tot = 0.0;
        #pragma unroll
        for (int x = 0; x < 8; ++x) tot += (double)atomicAdd(&hg8[x * 128 + t], 0.f);
        sm.tl.hgs[t] = (float)(tot / S);
    }
    __syncthreads();

    #pragma unroll
    for (int rep = 0; rep < 2; ++rep) {           // L1: 512 outputs, 2/thread
        int o = t + rep * 256;
        float acc = b1[o];
        #pragma unroll 4
        for (int d2 = 0; d2 < 128; ++d2) acc += sm.tl.hgs[d2] * W1[d2 * 512 + o];
        sm.tl.x1s[o] = fmaxf(acc, 0.f);
    }
    __syncthreads();

    {   // L2: 128 outputs, split-k 2
        int o = t & 127, half = t >> 7;
        float acc = 0.f;
        #pragma unroll 4
        for (int i = 0; i < 256; ++i) {
            int k = half * 256 + i;
            acc += sm.tl.x1s[k] * W2[k * 128 + o];
        }
        sm.tl.fpart[t] = acc;
        __syncthreads();
        if (t < 128) sm.tl.x2s[t] = fmaxf(sm.tl.fpart[t] + sm.tl.fpart[t + 128] + b2[t], 0.f);
    }
    __syncthreads();

    {   // L3: 16 outputs, 16 k-groups of 8
        int o = t & 15, g2 = t >> 4;
        float acc = 0.f;
        #pragma unroll
        for (int i = 0; i < 8; ++i) {
            int k = g2 * 8 + i;
            acc += sm.tl.x2s[k] * W3[k * 16 + o];
        }
        sm.tl.fpart[t] = acc;
        __syncthreads();
        if (t < 16) {
            float s3 = b3[t];
            #pragma unroll
            for (int g3 = 0; g3 < 16; ++g3) s3 += sm.tl.fpart[t + 16 * g3];
            sm.tl.x3s[t] = fmaxf(s3, 0.f);
        }
    }
    __syncthreads();

    if (t == 0) {
        float acc = b4[0];
        #pragma unroll
        for (int k = 0; k < 16; ++k) acc += sm.tl.x3s[k] * W4[k];
        out[0] = acc;
    }
}

extern "C" void kernel_launch(void* const* d_in, const int* in_sizes, int n_in,
                              void* d_out, int out_size, void* d_ws, size_t ws_size,
                              hipStream_t stream) {
    const float* h   = (const float*)d_in[0];
    const float* e   = (const float*)d_in[1];
    const int*   src = (const int*)d_in[2];
    const int*   dst = (const int*)d_in[3];
    const float* W_u = (const float*)d_in[4];
    const float* W_e = (const float*)d_in[5];
    const float* a   = (const float*)d_in[6];
    const float* W_m = (const float*)d_in[7];
    const float* W1  = (const float*)d_in[8];
    const float* b1  = (const float*)d_in[9];
    const float* W2  = (const float*)d_in[10];
    const float* b2  = (const float*)d_in[11];
    const float* W3  = (const float*)d_in[12];
    const float* b3  = (const float*)d_in[13];
    const float* W4  = (const float*)d_in[14];
    const float* b4  = (const float*)d_in[15];
    float* out = (float*)d_out;

    char* ws = (char*)d_ws;
    float*  ps    = (float*)(ws);                     // 50000 f
    float*  pd    = (float*)(ws + 200000);            // 50000 f
    float*  w8    = (float*)(ws + 400000);            // 8*50048 f = 1,601,536 B
    u16*    Bhi   = (u16*)(ws + 2001536);             // 32768 B
    u16*    Blo   = (u16*)(ws + 2034304);             // 32768 B
    float*  w_em  = (float*)(ws + 2067072);           // 256 B
    double* Spart = (double*)(ws + 2067328);          // 2048 d = 16384 B
    float*  hg8   = (float*)(ws + 2083712);           // 8*128 f = 4096 B
    int*    counter=(int*)(ws + 2087808);             // 4 B -> ends 2,087,812

    hipLaunchKernelGGL(kp_prep, dim3(KP_GRID), dim3(256), 0, stream,
                       W_u, W_e, W_m, Bhi, Blo, w8, hg8, w_em, counter);
    hipLaunchKernelGGL(kg_gemm, dim3(KG_BLKS), dim3(256), 0, stream,
                       h, a, Bhi, Blo, ps, pd);
    hipLaunchKernelGGL(keb_edge, dim3(KEB_GRID), dim3(256), 0, stream,
                       e, w_em, src, dst, ps, pd, w8, Spart);
    hipLaunchKernelGGL(kg2_hg_tail, dim3(KG_BLKS), dim3(256), 0, stream,
                       h, Bhi, Blo, w8, hg8, Spart, counter,
                       W1, b1, W2, b2, W3, b3, W4, b4, out);
}

// Round 19
// 88.000 us; speedup vs baseline: 1.4091x; 1.4091x over previous
//
#include <hip/hip_runtime.h>
#include <math.h>

#define N_NODES 50000
#define N_PAD   50048      // padded per-XCD slice stride
#define N_EDGES 600000
#define ALPHA 0.01f
#define KG_BLKS 782        // GEMM blocks (782*64 = 50048 >= 50000)
#define KEB_GRID 2048      // fused e+edge blocks
#define KP_GRID 64
#define N_SL 64            // hg8 slices (fan-in reduction)

typedef unsigned short u16;
typedef unsigned int u32;
using short8 = __attribute__((ext_vector_type(8))) short;
using f32x4  = __attribute__((ext_vector_type(4))) float;

__device__ __forceinline__ float leaky(float x) { return x > 0.f ? x : ALPHA * x; }

__device__ __forceinline__ u16 f2bf_rn(float x) {
    u32 u = __float_as_uint(x);
    u32 r = (u + 0x7FFFu + ((u >> 16) & 1u)) >> 16;
    return (u16)r;
}
__device__ __forceinline__ float bf2f(u16 b) { return __uint_as_float(((u32)b) << 16); }

// ====== KP: zero w8/hg64 + pack W_u into MFMA B-frag (bf16 hi/lo) + w_em =============
__global__ __launch_bounds__(256) void kp_prep(const float* __restrict__ Wu,
                                               const float* __restrict__ W_e,
                                               const float* __restrict__ W_m,
                                               u16* __restrict__ Bhi, u16* __restrict__ Blo,
                                               float* __restrict__ w8,
                                               float* __restrict__ hg64,
                                               float* __restrict__ w_em_g) {
    int g = blockIdx.x * 256 + threadIdx.x;
    for (int i = g; i < 8 * N_PAD; i += KP_GRID * 256) w8[i] = 0.f;
    if (g < N_SL * 128) hg64[g] = 0.f;           // 64 x 128 accumulator slices
    if (g < 2048) {
        int f = g >> 6;                          // nt*4+kt
        int L = g & 63;
        int nt = f >> 2, kt = f & 3;
        int kbase = kt * 32 + (L >> 4) * 8;
        int col = nt * 16 + (L & 15);
        #pragma unroll
        for (int j = 0; j < 8; ++j) {
            float x = Wu[(size_t)(kbase + j) * 128 + col];
            u16 hi = f2bf_rn(x);
            u16 lo = f2bf_rn(x - bf2f(hi));
            Bhi[(size_t)g * 8 + j] = hi;
            Blo[(size_t)g * 8 + j] = lo;
        }
    }
    if (g >= 2048 && g < 2112) {                 // 64 threads: w_em = W_e @ W_m
        int r = g - 2048;
        float acc = 0.f;
        const float* row = W_e + r * 128;
        #pragma unroll 8
        for (int k = 0; k < 128; ++k) acc += row[k] * W_m[k];
        w_em_g[r] = acc;
    }
}

// ================= KG: MFMA node GEMM -> ps, pd only (identical to R16) ==============
__global__ __launch_bounds__(256) void kg_gemm(
        const float* __restrict__ h, const float* __restrict__ a,
        const u16* __restrict__ Bhi, const u16* __restrict__ Blo,
        float* __restrict__ ps, float* __restrict__ pd) {
    __shared__ u16 sAhi[64 * 128];
    __shared__ u16 sAlo[64 * 128];
    __shared__ float sav[256];
    int t = threadIdx.x;
    int base = blockIdx.x * 64;
    if (t < 256) sav[t] = a[t];

    #pragma unroll
    for (int it = 0; it < 8; ++it) {
        int i = t + it * 256;
        int row = i >> 5, c4 = i & 31;
        float4 v = make_float4(0.f, 0.f, 0.f, 0.f);
        if (base + row < N_NODES)
            v = ((const float4*)h)[(size_t)(base + row) * 32 + c4];
        u16 h0 = f2bf_rn(v.x), h1 = f2bf_rn(v.y), h2 = f2bf_rn(v.z), h3 = f2bf_rn(v.w);
        u16 l0 = f2bf_rn(v.x - bf2f(h0)), l1 = f2bf_rn(v.y - bf2f(h1));
        u16 l2 = f2bf_rn(v.z - bf2f(h2)), l3 = f2bf_rn(v.w - bf2f(h3));
        uint2 whi = make_uint2((u32)h0 | ((u32)h1 << 16), (u32)h2 | ((u32)h3 << 16));
        uint2 wlo = make_uint2((u32)l0 | ((u32)l1 << 16), (u32)l2 | ((u32)l3 << 16));
        int idx = (row * 128 + c4 * 4) ^ ((row & 7) << 3);
        *(uint2*)(sAhi + idx) = whi;
        *(uint2*)(sAlo + idx) = wlo;
    }
    __syncthreads();

    int lane = t & 63;
    int wv = t >> 6;
    int khalf = lane >> 4;
    int l15 = lane & 15;

    short8 ahi[4], alo[4];
    {
        int rloc = wv * 16 + l15;
        #pragma unroll
        for (int kt = 0; kt < 4; ++kt) {
            int idx = (rloc * 128 + kt * 32 + khalf * 8) ^ ((rloc & 7) << 3);
            ahi[kt] = *(const short8*)(sAhi + idx);
            alo[kt] = *(const short8*)(sAlo + idx);
        }
    }

    float psum1[4] = {0.f, 0.f, 0.f, 0.f};
    float psum2[4] = {0.f, 0.f, 0.f, 0.f};

    #pragma unroll
    for (int nt = 0; nt < 8; ++nt) {
        f32x4 acc = {0.f, 0.f, 0.f, 0.f};
        #pragma unroll
        for (int kt = 0; kt < 4; ++kt) {
            size_t bi = ((size_t)(nt * 4 + kt) * 64 + lane) * 8;
            short8 bhi = *(const short8*)(Bhi + bi);
            short8 blo = *(const short8*)(Blo + bi);
            acc = __builtin_amdgcn_mfma_f32_16x16x32_bf16(ahi[kt], bhi, acc, 0, 0, 0);
            acc = __builtin_amdgcn_mfma_f32_16x16x32_bf16(alo[kt], bhi, acc, 0, 0, 0);
            acc = __builtin_amdgcn_mfma_f32_16x16x32_bf16(ahi[kt], blo, acc, 0, 0, 0);
        }
        int colg = nt * 16 + l15;
        float a1 = sav[colg], a2 = sav[128 + colg];
        #pragma unroll
        for (int r = 0; r < 4; ++r) {
            float o = leaky(acc[r]);
            psum1[r] += o * a1;
            psum2[r] += o * a2;
        }
    }

    #pragma unroll
    for (int r = 0; r < 4; ++r) {
        float p1 = psum1[r], p2 = psum2[r];
        #pragma unroll
        for (int m = 8; m >= 1; m >>= 1) {
            p1 += __shfl_xor(p1, m);
            p2 += __shfl_xor(p2, m);
        }
        if (l15 == 0) {
            int row = base + wv * 16 + khalf * 4 + r;
            if (row < N_NODES) { ps[row] = p1; pd[row] = p2; }
        }
    }
}

// ====== KEB: e-dot + sigmoid/exp + XCD-local w8 atomic + Spart (identical to R16) ====
__global__ __launch_bounds__(256) void keb_edge(
        const float* __restrict__ e, const float* __restrict__ w_em_g,
        const int* __restrict__ src, const int* __restrict__ dst,
        const float* __restrict__ ps, const float* __restrict__ pd,
        float* __restrict__ w8, double* __restrict__ Spart) {
    __shared__ float swem[64];
    int t = threadIdx.x;
    if (t < 64) swem[t] = w_em_g[t];
    __syncthreads();
    int lane = t & 63;
    int q = lane & 15;
    int g = lane >> 4;
    int gw = (blockIdx.x * 256 + t) >> 6;
    const int nw = KEB_GRID * 4;
    float4 wv = ((const float4*)swem)[q];
    float* wsl = w8 + (blockIdx.x & 7) * N_PAD;   // slice (fan-out reduction)

    double sacc = 0.0;
    for (int base = gw * 16; base < N_EDGES; base += nw * 16) {
        int o = base + g + 4 * (q & 3);           // finalize-edge for lanes with q<4
        int s  = src[o];
        int dd = dst[o];
        int e0 = base + g;                        // E%16==0 -> in range
        float4 v0 = ((const float4*)(e + (size_t)e0 * 64))[q];
        float4 v1 = ((const float4*)(e + (size_t)(e0 + 4) * 64))[q];
        float4 v2 = ((const float4*)(e + (size_t)(e0 + 8) * 64))[q];
        float4 v3 = ((const float4*)(e + (size_t)(e0 + 12) * 64))[q];
        float score = ps[s] + pd[dd];
        float sig = 1.f / (1.f + expf(-score));
        float d0 = v0.x * wv.x + v0.y * wv.y + v0.z * wv.z + v0.w * wv.w;
        float d1 = v1.x * wv.x + v1.y * wv.y + v1.z * wv.z + v1.w * wv.w;
        float d2 = v2.x * wv.x + v2.y * wv.y + v2.z * wv.z + v2.w * wv.w;
        float d3 = v3.x * wv.x + v3.y * wv.y + v3.z * wv.z + v3.w * wv.w;
        #pragma unroll
        for (int m = 1; m <= 8; m <<= 1) {
            d0 += __shfl_xor(d0, m);
            d1 += __shfl_xor(d1, m);
            d2 += __shfl_xor(d2, m);
            d3 += __shfl_xor(d3, m);
        }
        if (q < 4) {
            float dsel = (q == 0) ? d0 : (q == 1) ? d1 : (q == 2) ? d2 : d3;
            float p = expf(sig * dsel);
            atomicAdd(&wsl[s], p);
            sacc += (double)p;
        }
    }
    __shared__ double sred[256];
    sred[t] = sacc;
    __syncthreads();
    for (int s2_ = 128; s2_ > 0; s2_ >>= 1) {
        if (t < s2_) sred[t] += sred[t + s2_];
        __syncthreads();
    }
    if (t == 0) Spart[blockIdx.x] = sred[0];
}

// ====== KG2: recompute GEMM; parallel w8 staging; 64-slice hg64 atomics ==============
__global__ __launch_bounds__(256) void kg2_hg(
        const float* __restrict__ h, const u16* __restrict__ Bhi,
        const u16* __restrict__ Blo, const float* __restrict__ w8,
        float* __restrict__ hg64) {
    __shared__ u16 sAhi[64 * 128];
    __shared__ u16 sAlo[64 * 128];
    __shared__ float swpart[4][64];
    __shared__ float sredf[4][8][16];
    int t = threadIdx.x;
    int base = blockIdx.x * 64;

    // parallel w8 staging: 256 threads, 4 slice-groups x 64 rows, 2 slices each
    {
        int x2 = t >> 6, r = t & 63;              // rows beyond N_NODES are zero in w8
        swpart[x2][r] = w8[(size_t)x2 * N_PAD + base + r] +
                        w8[(size_t)(x2 + 4) * N_PAD + base + r];
    }

    #pragma unroll
    for (int it = 0; it < 8; ++it) {
        int i = t + it * 256;
        int row = i >> 5, c4 = i & 31;
        float4 v = make_float4(0.f, 0.f, 0.f, 0.f);
        if (base + row < N_NODES)
            v = ((const float4*)h)[(size_t)(base + row) * 32 + c4];
        u16 h0 = f2bf_rn(v.x), h1 = f2bf_rn(v.y), h2 = f2bf_rn(v.z), h3 = f2bf_rn(v.w);
        u16 l0 = f2bf_rn(v.x - bf2f(h0)), l1 = f2bf_rn(v.y - bf2f(h1));
        u16 l2 = f2bf_rn(v.z - bf2f(h2)), l3 = f2bf_rn(v.w - bf2f(h3));
        uint2 whi = make_uint2((u32)h0 | ((u32)h1 << 16), (u32)h2 | ((u32)h3 << 16));
        uint2 wlo = make_uint2((u32)l0 | ((u32)l1 << 16), (u32)l2 | ((u32)l3 << 16));
        int idx = (row * 128 + c4 * 4) ^ ((row & 7) << 3);
        *(uint2*)(sAhi + idx) = whi;
        *(uint2*)(sAlo + idx) = wlo;
    }
    __syncthreads();

    int lane = t & 63;
    int wv = t >> 6;
    int khalf = lane >> 4;
    int l15 = lane & 15;

    short8 ahi[4], alo[4];
    {
        int rloc = wv * 16 + l15;
        #pragma unroll
        for (int kt = 0; kt < 4; ++kt) {
            int idx = (rloc * 128 + kt * 32 + khalf * 8) ^ ((rloc & 7) << 3);
            ahi[kt] = *(const short8*)(sAhi + idx);
            alo[kt] = *(const short8*)(sAlo + idx);
        }
    }

    float wr[4];
    #pragma unroll
    for (int r = 0; r < 4; ++r) {
        int rloc = wv * 16 + khalf * 4 + r;
        wr[r] = swpart[0][rloc] + swpart[1][rloc] + swpart[2][rloc] + swpart[3][rloc];
    }

    #pragma unroll
    for (int nt = 0; nt < 8; ++nt) {
        f32x4 acc = {0.f, 0.f, 0.f, 0.f};
        #pragma unroll
        for (int kt = 0; kt < 4; ++kt) {
            size_t bi = ((size_t)(nt * 4 + kt) * 64 + lane) * 8;
            short8 bhi = *(const short8*)(Bhi + bi);
            short8 blo = *(const short8*)(Blo + bi);
            acc = __builtin_amdgcn_mfma_f32_16x16x32_bf16(ahi[kt], bhi, acc, 0, 0, 0);
            acc = __builtin_amdgcn_mfma_f32_16x16x32_bf16(alo[kt], bhi, acc, 0, 0, 0);
            acc = __builtin_amdgcn_mfma_f32_16x16x32_bf16(ahi[kt], blo, acc, 0, 0, 0);
        }
        float colsum = 0.f;
        #pragma unroll
        for (int r = 0; r < 4; ++r) colsum += leaky(acc[r]) * wr[r];
        colsum += __shfl_xor(colsum, 16);
        colsum += __shfl_xor(colsum, 32);
        if (khalf == 0) sredf[wv][nt][l15] = colsum;
    }
    __syncthreads();
    if (t < 128) {
        int nt = t >> 4, l = t & 15;
        float s = sredf[0][nt][l] + sredf[1][nt][l] + sredf[2][nt][l] + sredf[3][nt][l];
        atomicAdd(&hg64[(blockIdx.x & (N_SL - 1)) * 128 + t], s);  // 64-way fan-in cut
    }
}

// ====== KD: reduce S + hg64 slices, then MLP (single block) ==========================
__global__ __launch_bounds__(1024) void kd_tail(
        const double* __restrict__ Spart, const float* __restrict__ hg64,
        const float* __restrict__ W1, const float* __restrict__ b1,
        const float* __restrict__ W2, const float* __restrict__ b2,
        const float* __restrict__ W3, const float* __restrict__ b3,
        const float* __restrict__ W4, const float* __restrict__ b4,
        float* __restrict__ out) {
    __shared__ double dred[1024];
    __shared__ float fpart[1024];
    __shared__ float hgs[128];
    __shared__ float x1s[512];
    __shared__ float x2s[128];
    __shared__ float x3s[16];
    int t = threadIdx.x;

    dred[t] = Spart[t] + Spart[t + 1024];          // KEB_GRID == 2048
    __syncthreads();
    for (int st = 512; st > 0; st >>= 1) {
        if (t < st) dred[t] += dred[t + st];
        __syncthreads();
    }
    double S = dred[0];
    __syncthreads();

    {   // hg: 1024 threads sum 64 slices (8 groups x 8 slices each)
        int c = t & 127, g = t >> 7;
        double acc = 0.0;
        #pragma unroll
        for (int j = 0; j < 8; ++j)
            acc += (double)hg64[(g * 8 + j) * 128 + c];
        dred[t] = acc;
        __syncthreads();
        if (t < 128) {
            double tot = 0.0;
            #pragma unroll
            for (int g2 = 0; g2 < 8; ++g2) tot += dred[t + 128 * g2];
            hgs[t] = (float)(tot / S);
        }
    }
    __syncthreads();

    {   // L1
        int o = t & 511, g = t >> 9;
        float acc = 0.f;
        #pragma unroll 8
        for (int i = 0; i < 64; ++i) {
            int d = g * 64 + i;
            acc += hgs[d] * W1[d * 512 + o];
        }
        fpart[t] = acc;
        __syncthreads();
        if (t < 512) x1s[t] = fmaxf(fpart[t] + fpart[t + 512] + b1[t], 0.f);
    }
    __syncthreads();

    {   // L2
        int o = t & 127, g = t >> 7;
        float acc = 0.f;
        #pragma unroll 8
        for (int i = 0; i < 64; ++i) {
            int k = g * 64 + i;
            acc += x1s[k] * W2[k * 128 + o];
        }
        fpart[t] = acc;
        __syncthreads();
        if (t < 128) {
            float s2 = b2[t];
            #pragma unroll
            for (int g2 = 0; g2 < 8; ++g2) s2 += fpart[t + 128 * g2];
            x2s[t] = fmaxf(s2, 0.f);
        }
    }
    __syncthreads();

    {   // L3
        if (t < 256) {
            int o = t & 15, g = t >> 4;
            float acc = 0.f;
            #pragma unroll
            for (int i = 0; i < 8; ++i) {
                int k = g * 8 + i;
                acc += x2s[k] * W3[k * 16 + o];
            }
            fpart[t] = acc;
        }
        __syncthreads();
        if (t < 16) {
            float s3 = b3[t];
            #pragma unroll
            for (int g2 = 0; g2 < 16; ++g2) s3 += fpart[t + 16 * g2];
            x3s[t] = fmaxf(s3, 0.f);
        }
    }
    __syncthreads();

    if (t == 0) {
        float acc = b4[0];
        #pragma unroll
        for (int k = 0; k < 16; ++k) acc += x3s[k] * W4[k];
        out[0] = acc;
    }
}

extern "C" void kernel_launch(void* const* d_in, const int* in_sizes, int n_in,
                              void* d_out, int out_size, void* d_ws, size_t ws_size,
                              hipStream_t stream) {
    const float* h   = (const float*)d_in[0];
    const float* e   = (const float*)d_in[1];
    const int*   src = (const int*)d_in[2];
    const int*   dst = (const int*)d_in[3];
    const float* W_u = (const float*)d_in[4];
    const float* W_e = (const float*)d_in[5];
    const float* a   = (const float*)d_in[6];
    const float* W_m = (const float*)d_in[7];
    const float* W1  = (const float*)d_in[8];
    const float* b1  = (const float*)d_in[9];
    const float* W2  = (const float*)d_in[10];
    const float* b2  = (const float*)d_in[11];
    const float* W3  = (const float*)d_in[12];
    const float* b3  = (const float*)d_in[13];
    const float* W4  = (const float*)d_in[14];
    const float* b4  = (const float*)d_in[15];
    float* out = (float*)d_out;

    char* ws = (char*)d_ws;
    float*  ps    = (float*)(ws);                     // 50000 f
    float*  pd    = (float*)(ws + 200000);            // 50000 f
    float*  w8    = (float*)(ws + 400000);            // 8*50048 f = 1,601,536 B
    u16*    Bhi   = (u16*)(ws + 2001536);             // 32768 B
    u16*    Blo   = (u16*)(ws + 2034304);             // 32768 B
    float*  w_em  = (float*)(ws + 2067072);           // 256 B
    double* Spart = (double*)(ws + 2067328);          // 2048 d = 16384 B
    float*  hg64  = (float*)(ws + 2083712);           // 64*128 f = 32768 B -> 2,116,480

    hipLaunchKernelGGL(kp_prep, dim3(KP_GRID), dim3(256), 0, stream,
                       W_u, W_e, W_m, Bhi, Blo, w8, hg64, w_em);
    hipLaunchKernelGGL(kg_gemm, dim3(KG_BLKS), dim3(256), 0, stream,
                       h, a, Bhi, Blo, ps, pd);
    hipLaunchKernelGGL(keb_edge, dim3(KEB_GRID), dim3(256), 0, stream,
                       e, w_em, src, dst, ps, pd, w8, Spart);
    hipLaunchKernelGGL(kg2_hg, dim3(KG_BLKS), dim3(256), 0, stream,
                       h, Bhi, Blo, w8, hg64);
    hipLaunchKernelGGL(kd_tail, dim3(1), dim3(1024), 0, stream,
                       Spart, hg64, W1, b1, W2, b2, W3, b3, W4, b4, out);
}